// Round 1
// baseline (1479.850 us; speedup 1.0000x reference)
//
#include <hip/hip_runtime.h>

#define NSEG 100000
#define DIM 32
#define SCAN_THREADS 1024
#define SCAN_CHUNK ((NSEG + SCAN_THREADS - 1) / SCAN_THREADS)  // 98

// ---------------------------------------------------------------------------
// Fast path: counting-sort + segmented gather-reduce.
// Replaces 128M float device-atomics (measured ~1.2e11 atomics/s => ~1.1 ms)
// with 8M int atomics + pure coalesced reads.
// ---------------------------------------------------------------------------

__global__ void count_kernel(const int* __restrict__ idx,
                             int* __restrict__ counts, int n_rows) {
    int r = blockIdx.x * blockDim.x + threadIdx.x;
    if (r >= n_rows) return;
    atomicAdd(&counts[idx[r]], 1);
}

// Single-block exclusive scan of counts[NSEG] -> offsets[NSEG+1], cursor[NSEG].
// 100K elements / 1024 threads = 98 sequential per thread + 10-step LDS scan.
__global__ void scan_kernel(const int* __restrict__ counts,
                            int* __restrict__ offsets,
                            int* __restrict__ cursor) {
    __shared__ int lsum[SCAN_THREADS];
    int t = threadIdx.x;
    int base = t * SCAN_CHUNK;

    int s = 0;
    for (int k = 0; k < SCAN_CHUNK; ++k) {
        int i = base + k;
        if (i < NSEG) s += counts[i];
    }
    lsum[t] = s;
    __syncthreads();

    // Hillis-Steele inclusive scan over the 1024 partials.
    for (int off = 1; off < SCAN_THREADS; off <<= 1) {
        int v = (t >= off) ? lsum[t - off] : 0;
        __syncthreads();
        lsum[t] += v;
        __syncthreads();
    }

    int run = (t == 0) ? 0 : lsum[t - 1];  // exclusive base for this chunk
    for (int k = 0; k < SCAN_CHUNK; ++k) {
        int i = base + k;
        if (i < NSEG) {
            offsets[i] = run;
            cursor[i]  = run;
            run += counts[i];
        }
    }
    if (t == SCAN_THREADS - 1) offsets[NSEG] = run;  // == n_rows
}

__global__ void scatter_perm_kernel(const int* __restrict__ idx,
                                    int* __restrict__ cursor,
                                    int* __restrict__ perm, int n_rows) {
    int r = blockIdx.x * blockDim.x + threadIdx.x;
    if (r >= n_rows) return;
    int pos = atomicAdd(&cursor[idx[r]], 1);
    perm[pos] = r;
}

// One wave (64 lanes) per segment: two 32-lane halves each gather whole
// 128B rows of x (fully coalesced), accumulate in registers, combine via
// shfl_xor(32), fused divide, single coalesced 128B store. No atomics.
__global__ void segment_reduce_kernel(const float* __restrict__ x,
                                      const int* __restrict__ perm,
                                      const int* __restrict__ offsets,
                                      float* __restrict__ out) {
    int seg = blockIdx.x * (blockDim.x >> 6) + (threadIdx.x >> 6);
    if (seg >= NSEG) return;
    int lane = threadIdx.x & 63;
    int half = lane >> 5;   // which row of the pair this half-wave handles
    int col  = lane & 31;

    int start = offsets[seg];
    int end   = offsets[seg + 1];

    // 4-deep unrolled gather for memory-level parallelism (perm->x chain is
    // ~1100 cycles serial; 4 independent rows in flight per half-wave).
    float a0 = 0.0f, a1 = 0.0f;
    int j = start + half;
    for (; j + 6 < end; j += 8) {
        int r0 = perm[j];
        int r1 = perm[j + 2];
        int r2 = perm[j + 4];
        int r3 = perm[j + 6];
        a0 += x[(size_t)r0 * DIM + col];
        a1 += x[(size_t)r1 * DIM + col];
        a0 += x[(size_t)r2 * DIM + col];
        a1 += x[(size_t)r3 * DIM + col];
    }
    for (; j < end; j += 2) {
        a0 += x[(size_t)perm[j] * DIM + col];
    }
    float acc = a0 + a1;

    acc += __shfl_xor(acc, 32, 64);  // combine the two half-wave rows

    if (half == 0) {
        float cnt = (float)(end - start);
        out[(size_t)seg * DIM + col] = acc / fmaxf(cnt, 1.0f);
    }
}

// ---------------------------------------------------------------------------
// Fallback path (previously harness-verified): element-wise float atomics.
// Used only if the workspace is too small for the counting-sort buffers.
// ---------------------------------------------------------------------------

__global__ void scatter_sum_kernel(const float* __restrict__ x,
                                   const int* __restrict__ idx,
                                   float* __restrict__ sums,
                                   float* __restrict__ cnts,
                                   int n_elems) {
    int i = blockIdx.x * blockDim.x + threadIdx.x;
    if (i >= n_elems) return;
    int row = i >> 5;
    int col = i & 31;
    int seg = idx[row];
    atomicAdd(&sums[seg * DIM + col], x[i]);
    if (col == 0) {
        atomicAdd(&cnts[seg], 1.0f);
    }
}

__global__ void divide_kernel(float* __restrict__ out,
                              const float* __restrict__ cnts,
                              int n) {
    int i = blockIdx.x * blockDim.x + threadIdx.x;
    if (i >= n) return;
    float c = cnts[i >> 5];
    out[i] = out[i] / fmaxf(c, 1.0f);
}

// ---------------------------------------------------------------------------

extern "C" void kernel_launch(void* const* d_in, const int* in_sizes, int n_in,
                              void* d_out, int out_size, void* d_ws, size_t ws_size,
                              hipStream_t stream) {
    const float* x   = (const float*)d_in[0];
    const int*   idx = (const int*)d_in[1];
    float* out = (float*)d_out;

    int n_elems = in_sizes[0];        // 4,000,000 * 32
    int n_rows  = n_elems / DIM;      // 4,000,000

    const int threads = 256;

    // Workspace layout (ints): counts[NSEG] | offsets[NSEG+1] | cursor[NSEG] | perm[n_rows]
    size_t need = ((size_t)3 * NSEG + 1 + (size_t)n_rows) * sizeof(int);

    if (ws_size >= need) {
        int* counts  = (int*)d_ws;
        int* offsets = counts + NSEG;
        int* cursor  = offsets + NSEG + 1;
        int* perm    = cursor + NSEG;

        // Only counts needs zeroing (harness poisons ws with 0xAA).
        // offsets/cursor/perm are fully overwritten; d_out is fully written
        // by segment_reduce_kernel, so no d_out memset at all.
        hipMemsetAsync(counts, 0, (size_t)NSEG * sizeof(int), stream);

        int blocks = (n_rows + threads - 1) / threads;
        count_kernel<<<blocks, threads, 0, stream>>>(idx, counts, n_rows);
        scan_kernel<<<1, SCAN_THREADS, 0, stream>>>(counts, offsets, cursor);
        scatter_perm_kernel<<<blocks, threads, 0, stream>>>(idx, cursor, perm, n_rows);

        int segs_per_block = threads / 64;                         // 4 waves/block
        int rblocks = (NSEG + segs_per_block - 1) / segs_per_block; // 25000
        segment_reduce_kernel<<<rblocks, threads, 0, stream>>>(x, perm, offsets, out);
    } else {
        // Previously-verified atomic path.
        float* cnts = (float*)d_ws;
        hipMemsetAsync(d_out, 0, (size_t)out_size * sizeof(float), stream);
        hipMemsetAsync(d_ws, 0, (size_t)NSEG * sizeof(float), stream);

        int blocks = (n_elems + threads - 1) / threads;
        scatter_sum_kernel<<<blocks, threads, 0, stream>>>(x, idx, out, cnts, n_elems);

        int blocks2 = (out_size + threads - 1) / threads;
        divide_kernel<<<blocks2, threads, 0, stream>>>(out, cnts, out_size);
    }
}

// Round 2
// 1258.487 us; speedup vs baseline: 1.1759x; 1.1759x over previous
//
#include <hip/hip_runtime.h>

#define NSEG 100000
#define DIM 32
#define NBUCKET 500          // buckets of SEG_PER_BKT consecutive segments
#define SEG_PER_BKT 200      // NBUCKET * SEG_PER_BKT == NSEG exactly
#define RPB 16384            // rows per partition block (64 iters of 256 threads)
#define PTHREADS 256

// ---------------------------------------------------------------------------
// Fast path: coarse 500-way deterministic partition + per-bucket LDS reduce.
// Zero global float atomics; zero atomic-with-return; zero d_out memset.
// ---------------------------------------------------------------------------

// P1: per-block bucket histogram (transposed store for P2's sequential scan).
__global__ void p1_block_hist(const int* __restrict__ idx,
                              int* __restrict__ blockhist,
                              int n_rows, int nblk) {
    __shared__ int hist[NBUCKET];
    int t = threadIdx.x, blk = blockIdx.x;
    for (int i = t; i < NBUCKET; i += PTHREADS) hist[i] = 0;
    __syncthreads();
    int base = blk * RPB;
    for (int it = 0; it < RPB / PTHREADS; ++it) {
        int row = base + it * PTHREADS + t;
        if (row < n_rows) {
            int b = idx[row] / SEG_PER_BKT;
            atomicAdd(&hist[b], 1);
        }
    }
    __syncthreads();
    for (int i = t; i < NBUCKET; i += PTHREADS)
        blockhist[(size_t)i * nblk + blk] = hist[i];
}

// P2: per bucket, exclusive scan over the block dimension (in place) + total.
__global__ void p2_scan_blocks(int* __restrict__ blockhist,
                               int* __restrict__ totals, int nblk) {
    int bkt = blockIdx.x;
    int lane = threadIdx.x;                 // 64 threads = 1 wave
    int* rowp = blockhist + (size_t)bkt * nblk;
    int cpl = (nblk + 63) / 64;
    int s0 = lane * cpl;
    int s1 = min(nblk, s0 + cpl);
    int csum = 0;
    for (int i = s0; i < s1; ++i) csum += rowp[i];
    int v = csum;                            // wave inclusive scan
    for (int d = 1; d < 64; d <<= 1) {
        int u = __shfl_up(v, d, 64);
        if (lane >= d) v += u;
    }
    int run = v - csum;                      // exclusive base for this chunk
    for (int i = s0; i < s1; ++i) {
        int h = rowp[i];
        rowp[i] = run;
        run += h;
    }
    int tot = __shfl(v, 63, 64);
    if (lane == 0) totals[bkt] = tot;
}

// P3: exclusive scan of 500 bucket totals -> bucket_base[0..NBUCKET].
__global__ void p3_scan_buckets(const int* __restrict__ totals,
                                int* __restrict__ bucket_base) {
    int lane = threadIdx.x;                 // 64 threads = 1 wave
    const int cpl = (NBUCKET + 63) / 64;    // 8
    int s0 = lane * cpl;
    int s1 = min(NBUCKET, s0 + cpl);
    int csum = 0;
    for (int i = s0; i < s1; ++i) csum += totals[i];
    int v = csum;
    for (int d = 1; d < 64; d <<= 1) {
        int u = __shfl_up(v, d, 64);
        if (lane >= d) v += u;
    }
    int run = v - csum;
    for (int i = s0; i < s1; ++i) {
        bucket_base[i] = run;
        run += totals[i];
    }
    if (lane == 63) bucket_base[NBUCKET] = v;
}

// P4: scatter rows into bucket-partitioned perm. Positions for a
// (block,bucket) pair are contiguous and written only by this block,
// so stores merge in this XCD's write-back L2 (kills the 241MB write amp).
// perm entry packs (local_seg << 24) | row so P5 never re-reads idx.
__global__ void p4_partition(const int* __restrict__ idx,
                             const int* __restrict__ blockhist,
                             const int* __restrict__ bucket_base,
                             unsigned int* __restrict__ perm,
                             int n_rows, int nblk) {
    __shared__ int cnt[NBUCKET];
    int t = threadIdx.x, blk = blockIdx.x;
    for (int i = t; i < NBUCKET; i += PTHREADS) cnt[i] = 0;
    __syncthreads();
    int base = blk * RPB;
    for (int it = 0; it < RPB / PTHREADS; ++it) {
        int row = base + it * PTHREADS + t;
        if (row < n_rows) {
            int seg = idx[row];
            int b = seg / SEG_PER_BKT;
            int rank = atomicAdd(&cnt[b], 1);
            int pos = bucket_base[b] + blockhist[(size_t)b * nblk + blk] + rank;
            perm[pos] = ((unsigned int)(seg - b * SEG_PER_BKT) << 24) |
                        (unsigned int)row;
        }
    }
}

// P5: one block per bucket. Half-wave (32 lanes) per row: coalesced 128B
// x-row gather, native LDS float atomics (bank-conflict-free: col==bank),
// fused count + divide, direct final store. No global atomics.
__global__ void __launch_bounds__(1024)
p5_bucket_reduce(const float* __restrict__ x,
                 const unsigned int* __restrict__ perm,
                 const int* __restrict__ bucket_base,
                 float* __restrict__ out) {
    __shared__ float sums[SEG_PER_BKT * DIM];   // 25.6 KB
    __shared__ int cnts[SEG_PER_BKT];
    int t = threadIdx.x;
    int b = blockIdx.x;
    for (int i = t; i < SEG_PER_BKT * DIM; i += 1024) sums[i] = 0.0f;
    for (int i = t; i < SEG_PER_BKT; i += 1024) cnts[i] = 0;
    __syncthreads();

    int start = bucket_base[b];
    int end   = bucket_base[b + 1];
    int hw  = t >> 5;       // 32 half-waves per block
    int col = t & 31;

    // 4-deep unroll: 4 independent perm->x chains per half-wave for MLP.
    int j = start + hw;
    for (; j + 96 < end; j += 128) {
        unsigned int p0 = perm[j];
        unsigned int p1 = perm[j + 32];
        unsigned int p2 = perm[j + 64];
        unsigned int p3 = perm[j + 96];
        float v0 = x[(size_t)(p0 & 0xFFFFFFu) * DIM + col];
        float v1 = x[(size_t)(p1 & 0xFFFFFFu) * DIM + col];
        float v2 = x[(size_t)(p2 & 0xFFFFFFu) * DIM + col];
        float v3 = x[(size_t)(p3 & 0xFFFFFFu) * DIM + col];
        atomicAdd(&sums[(p0 >> 24) * DIM + col], v0);
        atomicAdd(&sums[(p1 >> 24) * DIM + col], v1);
        atomicAdd(&sums[(p2 >> 24) * DIM + col], v2);
        atomicAdd(&sums[(p3 >> 24) * DIM + col], v3);
        if (col == 0) {
            atomicAdd(&cnts[p0 >> 24], 1);
            atomicAdd(&cnts[p1 >> 24], 1);
            atomicAdd(&cnts[p2 >> 24], 1);
            atomicAdd(&cnts[p3 >> 24], 1);
        }
    }
    for (; j < end; j += 32) {
        unsigned int p = perm[j];
        float v = x[(size_t)(p & 0xFFFFFFu) * DIM + col];
        atomicAdd(&sums[(p >> 24) * DIM + col], v);
        if (col == 0) atomicAdd(&cnts[p >> 24], 1);
    }
    __syncthreads();

    for (int e = t; e < SEG_PER_BKT * DIM; e += 1024) {
        int ls = e >> 5;
        float c = (float)cnts[ls];
        out[(size_t)b * SEG_PER_BKT * DIM + e] = sums[e] / fmaxf(c, 1.0f);
    }
}

// ---------------------------------------------------------------------------
// Fallback path (harness-verified in round 0): element-wise float atomics.
// ---------------------------------------------------------------------------

__global__ void scatter_sum_kernel(const float* __restrict__ x,
                                   const int* __restrict__ idx,
                                   float* __restrict__ sums,
                                   float* __restrict__ cnts,
                                   int n_elems) {
    int i = blockIdx.x * blockDim.x + threadIdx.x;
    if (i >= n_elems) return;
    int row = i >> 5;
    int col = i & 31;
    int seg = idx[row];
    atomicAdd(&sums[seg * DIM + col], x[i]);
    if (col == 0) atomicAdd(&cnts[seg], 1.0f);
}

__global__ void divide_kernel(float* __restrict__ out,
                              const float* __restrict__ cnts, int n) {
    int i = blockIdx.x * blockDim.x + threadIdx.x;
    if (i >= n) return;
    float c = cnts[i >> 5];
    out[i] = out[i] / fmaxf(c, 1.0f);
}

// ---------------------------------------------------------------------------

extern "C" void kernel_launch(void* const* d_in, const int* in_sizes, int n_in,
                              void* d_out, int out_size, void* d_ws, size_t ws_size,
                              hipStream_t stream) {
    const float* x   = (const float*)d_in[0];
    const int*   idx = (const int*)d_in[1];
    float* out = (float*)d_out;

    int n_elems = in_sizes[0];        // 4,000,000 * 32
    int n_rows  = n_elems / DIM;      // 4,000,000
    int nblk    = (n_rows + RPB - 1) / RPB;   // 245

    // ws (ints): perm[n_rows] | blockhist[NBUCKET*nblk] | totals[NBUCKET] | base[NBUCKET+1]
    size_t need = ((size_t)n_rows + (size_t)NBUCKET * nblk + NBUCKET + NBUCKET + 1)
                  * sizeof(int);

    if (ws_size >= need && n_rows <= (1 << 24)) {
        unsigned int* perm = (unsigned int*)d_ws;
        int* blockhist   = (int*)(perm + n_rows);
        int* totals      = blockhist + (size_t)NBUCKET * nblk;
        int* bucket_base = totals + NBUCKET;

        // No memsets needed: every ws/out element is fully written in-kernel.
        p1_block_hist<<<nblk, PTHREADS, 0, stream>>>(idx, blockhist, n_rows, nblk);
        p2_scan_blocks<<<NBUCKET, 64, 0, stream>>>(blockhist, totals, nblk);
        p3_scan_buckets<<<1, 64, 0, stream>>>(totals, bucket_base);
        p4_partition<<<nblk, PTHREADS, 0, stream>>>(idx, blockhist, bucket_base,
                                                    perm, n_rows, nblk);
        p5_bucket_reduce<<<NBUCKET, 1024, 0, stream>>>(x, perm, bucket_base, out);
    } else {
        float* cnts = (float*)d_ws;
        hipMemsetAsync(d_out, 0, (size_t)out_size * sizeof(float), stream);
        hipMemsetAsync(d_ws, 0, (size_t)NSEG * sizeof(float), stream);

        const int threads = 256;
        int blocks = (n_elems + threads - 1) / threads;
        scatter_sum_kernel<<<blocks, threads, 0, stream>>>(x, idx, out, cnts, n_elems);
        int blocks2 = (out_size + threads - 1) / threads;
        divide_kernel<<<blocks2, threads, 0, stream>>>(out, cnts, out_size);
    }
}

// Round 3
// 1229.027 us; speedup vs baseline: 1.2041x; 1.0240x over previous
//
#include <hip/hip_runtime.h>

#define NSEG 100000
#define DIM 32
#define NBUCKET 500          // buckets of SEG_PER_BKT consecutive segments
#define SEG_PER_BKT 200      // NBUCKET * SEG_PER_BKT == NSEG
#define RPB 8192             // rows per partition block
#define PTHREADS 256
#define RTHREADS 1024        // p5 block size
#define CHUNK 2048           // perm entries staged in LDS per step
#define SUMSTRIDE 33         // +1 pad: spreads 4-col-per-lane ds_add across banks

// ---------------------------------------------------------------------------
// P1: per-block bucket histogram (transposed for P2's per-bucket scan).
// ---------------------------------------------------------------------------
__global__ void p1_block_hist(const int* __restrict__ idx,
                              int* __restrict__ blockhist,
                              int n_rows, int nblk) {
    __shared__ int hist[NBUCKET];
    int t = threadIdx.x, blk = blockIdx.x;
    for (int i = t; i < NBUCKET; i += PTHREADS) hist[i] = 0;
    __syncthreads();
    int base = blk * RPB;
#pragma unroll
    for (int it = 0; it < RPB / PTHREADS; ++it) {
        int row = base + it * PTHREADS + t;
        if (row < n_rows) atomicAdd(&hist[idx[row] / SEG_PER_BKT], 1);
    }
    __syncthreads();
    for (int i = t; i < NBUCKET; i += PTHREADS)
        blockhist[(size_t)i * nblk + blk] = hist[i];
}

// ---------------------------------------------------------------------------
// P2: per bucket, exclusive scan over the block dimension (in place) + total.
// ---------------------------------------------------------------------------
__global__ void p2_scan_blocks(int* __restrict__ blockhist,
                               int* __restrict__ totals, int nblk) {
    int bkt = blockIdx.x;
    int lane = threadIdx.x;                 // 64 threads = 1 wave
    int* rowp = blockhist + (size_t)bkt * nblk;
    int cpl = (nblk + 63) / 64;
    int s0 = lane * cpl;
    int s1 = min(nblk, s0 + cpl);
    int csum = 0;
    for (int i = s0; i < s1; ++i) csum += rowp[i];
    int v = csum;
    for (int d = 1; d < 64; d <<= 1) {
        int u = __shfl_up(v, d, 64);
        if (lane >= d) v += u;
    }
    int run = v - csum;
    for (int i = s0; i < s1; ++i) {
        int h = rowp[i];
        rowp[i] = run;
        run += h;
    }
    int tot = __shfl(v, 63, 64);
    if (lane == 0) totals[bkt] = tot;
}

// ---------------------------------------------------------------------------
// P3: exclusive scan of 500 bucket totals -> bucket_base[0..NBUCKET].
// ---------------------------------------------------------------------------
__global__ void p3_scan_buckets(const int* __restrict__ totals,
                                int* __restrict__ bucket_base) {
    int lane = threadIdx.x;                 // 64 threads = 1 wave
    const int cpl = (NBUCKET + 63) / 64;    // 8
    int s0 = lane * cpl;
    int s1 = min(NBUCKET, s0 + cpl);
    int csum = 0;
    for (int i = s0; i < s1; ++i) csum += totals[i];
    int v = csum;
    for (int d = 1; d < 64; d <<= 1) {
        int u = __shfl_up(v, d, 64);
        if (lane >= d) v += u;
    }
    int run = v - csum;
    for (int i = s0; i < s1; ++i) {
        bucket_base[i] = run;
        run += totals[i];
    }
    if (lane == 63) bucket_base[NBUCKET] = v;
}

// ---------------------------------------------------------------------------
// P4: block-local counting sort in LDS, then fully COALESCED perm write-out.
// LDS buf entry packs (seg:17 | localrow:13); global perm packs
// (local_seg:8 | row:24) so P5 never re-reads idx.
// ---------------------------------------------------------------------------
__global__ void __launch_bounds__(PTHREADS)
p4_partition(const int* __restrict__ idx,
             const int* __restrict__ blockhist,
             const int* __restrict__ bucket_base,
             unsigned int* __restrict__ perm,
             int n_rows, int nblk) {
    __shared__ int scanb[NBUCKET + 1];
    __shared__ int cnt[NBUCKET];
    __shared__ unsigned int buf[RPB];
    int t = threadIdx.x, blk = blockIdx.x;
    int base = blk * RPB;
    int rows_blk = min(RPB, n_rows - base);

    for (int i = t; i < NBUCKET; i += PTHREADS) cnt[i] = 0;
    __syncthreads();

    // pass A: local bucket histogram; cache seg values in registers
    int segs[RPB / PTHREADS];
#pragma unroll
    for (int it = 0; it < RPB / PTHREADS; ++it) {
        int lr = it * PTHREADS + t;
        int seg = -1;
        if (lr < rows_blk) {
            seg = idx[base + lr];
            atomicAdd(&cnt[seg / SEG_PER_BKT], 1);
        }
        segs[it] = seg;
    }
    __syncthreads();

    // exclusive scan of cnt[500] by wave 0
    if (t < 64) {
        const int cpl = (NBUCKET + 63) / 64;  // 8
        int s0 = t * cpl, s1 = min(NBUCKET, s0 + cpl);
        int csum = 0;
        for (int i = s0; i < s1; ++i) csum += cnt[i];
        int v = csum;
        for (int d = 1; d < 64; d <<= 1) {
            int u = __shfl_up(v, d, 64);
            if (t >= d) v += u;
        }
        int run = v - csum;
        for (int i = s0; i < s1; ++i) {
            scanb[i] = run;
            run += cnt[i];
        }
        if (t == 63) scanb[NBUCKET] = v;
    }
    __syncthreads();
    for (int i = t; i < NBUCKET; i += PTHREADS) cnt[i] = 0;
    __syncthreads();

    // pass B: rank-scatter into bucket-ordered LDS buffer
#pragma unroll
    for (int it = 0; it < RPB / PTHREADS; ++it) {
        int seg = segs[it];
        if (seg >= 0) {
            int b = seg / SEG_PER_BKT;
            int slot = scanb[b] + atomicAdd(&cnt[b], 1);
            buf[slot] = ((unsigned int)seg << 13) |
                        (unsigned int)(it * PTHREADS + t);
        }
    }
    __syncthreads();

    // pass C: coalesced write-out (consecutive slots -> consecutive gpos)
    for (int s = t; s < rows_blk; s += PTHREADS) {
        unsigned int e = buf[s];
        int seg = (int)(e >> 13);
        int lr  = (int)(e & 8191u);
        int b   = seg / SEG_PER_BKT;
        int ls  = seg - b * SEG_PER_BKT;
        int gpos = bucket_base[b] + blockhist[(size_t)b * nblk + blk]
                 + (s - scanb[b]);
        perm[gpos] = ((unsigned int)ls << 24) | (unsigned int)(base + lr);
    }
}

// ---------------------------------------------------------------------------
// P5: one block per bucket. perm staged in LDS (double-buffered, async-split
// prefetch) so the gather loop has no global dependency on perm. float4 row
// gather: 8 lanes/row -> one wave load = 8 rows (1KB) in flight. LDS float
// atomics with stride-33 padding (~2-way banks). Fused divide, direct store.
// ---------------------------------------------------------------------------
__global__ void __launch_bounds__(RTHREADS)
p5_bucket_reduce(const float* __restrict__ x,
                 const unsigned int* __restrict__ perm,
                 const int* __restrict__ bucket_base,
                 float* __restrict__ out) {
    __shared__ float sums[SEG_PER_BKT * SUMSTRIDE];   // 26.4 KB
    __shared__ int cnts[SEG_PER_BKT];
    __shared__ unsigned int pbuf[2][CHUNK];           // 16 KB
    int t = threadIdx.x;
    int b = blockIdx.x;
    for (int i = t; i < SEG_PER_BKT * SUMSTRIDE; i += RTHREADS) sums[i] = 0.0f;
    for (int i = t; i < SEG_PER_BKT; i += RTHREADS) cnts[i] = 0;

    int start = bucket_base[b];
    int end   = bucket_base[b + 1];
    int total = end - start;

    const float4* x4 = (const float4*)x;
    int g   = t >> 3;    // 128 groups of 8 lanes
    int sub = t & 7;

    // preload chunk 0
    int m0 = min(CHUNK, total);
    for (int i = t; i < m0; i += RTHREADS) pbuf[0][i] = perm[start + i];
    __syncthreads();

    int nchunks = (total + CHUNK - 1) / CHUNK;
    for (int c = 0; c < nchunks; ++c) {
        int cb  = start + c * CHUNK;
        int m   = min(CHUNK, end - cb);
        int cur = c & 1, nxt = cur ^ 1;

        // T14 async-split: ISSUE next-chunk loads now (latency hides under
        // the gather phase); LDS-write them after the compute.
        unsigned int r0 = 0, r1 = 0;
        int nm = 0;
        if (c + 1 < nchunks) {
            int nb = cb + CHUNK;
            nm = min(CHUNK, end - nb);
            if (t < nm)          r0 = perm[nb + t];
            if (t + 1024 < nm)   r1 = perm[nb + t + 1024];
        }

        // gather + accumulate from current chunk (4 independent chains)
        int i = g;
        for (; i + 384 < m; i += 512) {
            unsigned int e0 = pbuf[cur][i];
            unsigned int e1 = pbuf[cur][i + 128];
            unsigned int e2 = pbuf[cur][i + 256];
            unsigned int e3 = pbuf[cur][i + 384];
            float4 v0 = x4[(size_t)(e0 & 0xFFFFFFu) * 8 + sub];
            float4 v1 = x4[(size_t)(e1 & 0xFFFFFFu) * 8 + sub];
            float4 v2 = x4[(size_t)(e2 & 0xFFFFFFu) * 8 + sub];
            float4 v3 = x4[(size_t)(e3 & 0xFFFFFFu) * 8 + sub];
            int s0 = (int)(e0 >> 24) * SUMSTRIDE + sub * 4;
            int s1 = (int)(e1 >> 24) * SUMSTRIDE + sub * 4;
            int s2 = (int)(e2 >> 24) * SUMSTRIDE + sub * 4;
            int s3 = (int)(e3 >> 24) * SUMSTRIDE + sub * 4;
            atomicAdd(&sums[s0 + 0], v0.x); atomicAdd(&sums[s0 + 1], v0.y);
            atomicAdd(&sums[s0 + 2], v0.z); atomicAdd(&sums[s0 + 3], v0.w);
            atomicAdd(&sums[s1 + 0], v1.x); atomicAdd(&sums[s1 + 1], v1.y);
            atomicAdd(&sums[s1 + 2], v1.z); atomicAdd(&sums[s1 + 3], v1.w);
            atomicAdd(&sums[s2 + 0], v2.x); atomicAdd(&sums[s2 + 1], v2.y);
            atomicAdd(&sums[s2 + 2], v2.z); atomicAdd(&sums[s2 + 3], v2.w);
            atomicAdd(&sums[s3 + 0], v3.x); atomicAdd(&sums[s3 + 1], v3.y);
            atomicAdd(&sums[s3 + 2], v3.z); atomicAdd(&sums[s3 + 3], v3.w);
            if (sub == 0) {
                atomicAdd(&cnts[e0 >> 24], 1);
                atomicAdd(&cnts[e1 >> 24], 1);
                atomicAdd(&cnts[e2 >> 24], 1);
                atomicAdd(&cnts[e3 >> 24], 1);
            }
        }
        for (; i < m; i += 128) {
            unsigned int e = pbuf[cur][i];
            float4 v = x4[(size_t)(e & 0xFFFFFFu) * 8 + sub];
            int s0 = (int)(e >> 24) * SUMSTRIDE + sub * 4;
            atomicAdd(&sums[s0 + 0], v.x); atomicAdd(&sums[s0 + 1], v.y);
            atomicAdd(&sums[s0 + 2], v.z); atomicAdd(&sums[s0 + 3], v.w);
            if (sub == 0) atomicAdd(&cnts[e >> 24], 1);
        }

        // write prefetched entries to the other buffer
        if (c + 1 < nchunks) {
            if (t < nm)        pbuf[nxt][t] = r0;
            if (t + 1024 < nm) pbuf[nxt][t + 1024] = r1;
        }
        __syncthreads();
    }

    // epilogue: fused divide + coalesced store (unpad stride 33 -> 32)
    for (int e = t; e < SEG_PER_BKT * DIM; e += RTHREADS) {
        int ls  = e >> 5;
        int col = e & 31;
        float cf = (float)cnts[ls];
        out[(size_t)b * SEG_PER_BKT * DIM + e] =
            sums[ls * SUMSTRIDE + col] / fmaxf(cf, 1.0f);
    }
}

// ---------------------------------------------------------------------------
// Fallback path (harness-verified in round 0): element-wise float atomics.
// ---------------------------------------------------------------------------
__global__ void scatter_sum_kernel(const float* __restrict__ x,
                                   const int* __restrict__ idx,
                                   float* __restrict__ sums,
                                   float* __restrict__ cnts,
                                   int n_elems) {
    int i = blockIdx.x * blockDim.x + threadIdx.x;
    if (i >= n_elems) return;
    int row = i >> 5;
    int col = i & 31;
    int seg = idx[row];
    atomicAdd(&sums[seg * DIM + col], x[i]);
    if (col == 0) atomicAdd(&cnts[seg], 1.0f);
}

__global__ void divide_kernel(float* __restrict__ out,
                              const float* __restrict__ cnts, int n) {
    int i = blockIdx.x * blockDim.x + threadIdx.x;
    if (i >= n) return;
    float c = cnts[i >> 5];
    out[i] = out[i] / fmaxf(c, 1.0f);
}

// ---------------------------------------------------------------------------

extern "C" void kernel_launch(void* const* d_in, const int* in_sizes, int n_in,
                              void* d_out, int out_size, void* d_ws, size_t ws_size,
                              hipStream_t stream) {
    const float* x   = (const float*)d_in[0];
    const int*   idx = (const int*)d_in[1];
    float* out = (float*)d_out;

    int n_elems = in_sizes[0];        // 4,000,000 * 32
    int n_rows  = n_elems / DIM;      // 4,000,000
    int nblk    = (n_rows + RPB - 1) / RPB;   // 489

    // ws (ints): perm[n_rows] | blockhist[NBUCKET*nblk] | totals | base[NBUCKET+1]
    size_t need = ((size_t)n_rows + (size_t)NBUCKET * nblk + NBUCKET + NBUCKET + 1)
                  * sizeof(int);

    if (ws_size >= need && n_rows <= (1 << 24)) {
        unsigned int* perm = (unsigned int*)d_ws;
        int* blockhist   = (int*)(perm + n_rows);
        int* totals      = blockhist + (size_t)NBUCKET * nblk;
        int* bucket_base = totals + NBUCKET;

        // No memsets: every ws/out element consumed is written in-kernel first.
        p1_block_hist<<<nblk, PTHREADS, 0, stream>>>(idx, blockhist, n_rows, nblk);
        p2_scan_blocks<<<NBUCKET, 64, 0, stream>>>(blockhist, totals, nblk);
        p3_scan_buckets<<<1, 64, 0, stream>>>(totals, bucket_base);
        p4_partition<<<nblk, PTHREADS, 0, stream>>>(idx, blockhist, bucket_base,
                                                    perm, n_rows, nblk);
        p5_bucket_reduce<<<NBUCKET, RTHREADS, 0, stream>>>(x, perm, bucket_base, out);
    } else {
        float* cnts = (float*)d_ws;
        hipMemsetAsync(d_out, 0, (size_t)out_size * sizeof(float), stream);
        hipMemsetAsync(d_ws, 0, (size_t)NSEG * sizeof(float), stream);

        const int threads = 256;
        int blocks = (n_elems + threads - 1) / threads;
        scatter_sum_kernel<<<blocks, threads, 0, stream>>>(x, idx, out, cnts, n_elems);
        int blocks2 = (out_size + threads - 1) / threads;
        divide_kernel<<<blocks2, threads, 0, stream>>>(out, cnts, out_size);
    }
}